// Round 1
// baseline (869.180 us; speedup 1.0000x reference)
//
#include <hip/hip_runtime.h>
#include <hip/hip_bf16.h>

// Problem: RobertaSelfAttention, B=8,S=1024,HID=1024,H=16,D=64, relative_key_query,
// with the source bug v = key-projection. Output f32 [B,S,HID].

#define BATCH 8
#define SEQ   1024
#define NHEAD 16
#define HDIM  64

typedef float  f32x4 __attribute__((ext_vector_type(4)));
typedef short  s16x8 __attribute__((ext_vector_type(8)));

#define MFMA16(a,b,c) __builtin_amdgcn_mfma_f32_16x16x32_bf16((a),(b),(c),0,0,0)

static __device__ __forceinline__ unsigned short f2b(float x){
    unsigned int u = __float_as_uint(x);
    unsigned int r = (u + 0x7fffu + ((u >> 16) & 1u)) >> 16;
    return (unsigned short)r;
}
static __device__ __forceinline__ float b2f(unsigned short b){
    return __uint_as_float(((unsigned int)b) << 16);
}

// ---------------- prep: dist_table f32 -> bf16 (2048 rows, last row zeroed) ------
__global__ void prep_table(const float* __restrict__ T, unsigned short* __restrict__ Tb){
    int i = blockIdx.x * 256 + threadIdx.x;           // 0 .. 131071
    if (i < 2047 * 64)      Tb[i] = f2b(T[i]);
    else if (i < 2048 * 64) Tb[i] = 0;
}

// ---------------- projection GEMM (bf16x3 for ~fp32 accuracy) --------------------
// C[8192 x 2048]: cols 0..1023 -> q, 1024..2047 -> k (also stored transposed as kT).
// grid: 1024 blocks (ntile = bx&15, mtile = bx>>4), 512 threads.
__global__ __launch_bounds__(512)
void proj_gemm(const float* __restrict__ Hs,
               const float* __restrict__ Wq, const float* __restrict__ bq,
               const float* __restrict__ Wk, const float* __restrict__ bk,
               unsigned short* __restrict__ qbf, unsigned short* __restrict__ kbf,
               unsigned short* __restrict__ kTbf)
{
    __shared__ unsigned short AhiL[128][40];
    __shared__ unsigned short AloL[128][40];
    __shared__ unsigned short BhiL[128][40];
    __shared__ unsigned short BloL[128][40];

    const int t     = threadIdx.x;
    const int ntile = blockIdx.x & 15;
    const int mtile = blockIdx.x >> 4;
    const int m0    = mtile * 128;
    const int cn0   = (ntile & 7) * 128;
    const float* Wsrc = (ntile < 8) ? Wq : Wk;

    const int lane = t & 63, w = t >> 6;
    const int q4 = lane >> 4, l15 = lane & 15;
    const int wm = w >> 1, wn = w & 1;

    f32x4 acc[2][4];
#pragma unroll
    for (int i = 0; i < 2; i++)
#pragma unroll
        for (int j = 0; j < 4; j++) acc[i][j] = (f32x4){0.f, 0.f, 0.f, 0.f};

    const int arow = t >> 2, ac8 = (t & 3) * 8;    // A stage: 128 rows x 32 cols
    const int bkr  = t >> 4, bnc8 = (t & 15) * 8;  // B stage: 32 k x 128 n

    for (int kk0 = 0; kk0 < 1024; kk0 += 32) {
        // ---- stage A (f32 -> hi/lo bf16) ----
        const float* ap = Hs + (size_t)(m0 + arow) * 1024 + kk0 + ac8;
        float av[8];
        *(f32x4*)&av[0] = *(const f32x4*)ap;
        *(f32x4*)&av[4] = *(const f32x4*)(ap + 4);
        unsigned short hi8[8], lo8[8];
#pragma unroll
        for (int j = 0; j < 8; j++) {
            unsigned short h = f2b(av[j]);
            hi8[j] = h;
            lo8[j] = f2b(av[j] - b2f(h));
        }
        *(s16x8*)&AhiL[arow][ac8] = *(s16x8*)hi8;
        *(s16x8*)&AloL[arow][ac8] = *(s16x8*)lo8;

        // ---- stage B transposed (W[k][n] -> LDS[n][k]) ----
        const float* bp = Wsrc + (size_t)(kk0 + bkr) * 1024 + cn0 + bnc8;
        float bv[8];
        *(f32x4*)&bv[0] = *(const f32x4*)bp;
        *(f32x4*)&bv[4] = *(const f32x4*)(bp + 4);
#pragma unroll
        for (int j = 0; j < 8; j++) {
            unsigned short h = f2b(bv[j]);
            BhiL[bnc8 + j][bkr] = h;
            BloL[bnc8 + j][bkr] = f2b(bv[j] - b2f(h));
        }
        __syncthreads();

        // ---- MFMA: 2x4 subtiles, 3 passes (hi*hi, hi*lo, lo*hi) ----
        s16x8 ah[2], al[2], bh8[4], bl8[4];
#pragma unroll
        for (int sm = 0; sm < 2; sm++) {
            int r = wm * 32 + sm * 16 + l15;
            ah[sm] = *(const s16x8*)&AhiL[r][q4 * 8];
            al[sm] = *(const s16x8*)&AloL[r][q4 * 8];
        }
#pragma unroll
        for (int sn = 0; sn < 4; sn++) {
            int r = wn * 64 + sn * 16 + l15;
            bh8[sn] = *(const s16x8*)&BhiL[r][q4 * 8];
            bl8[sn] = *(const s16x8*)&BloL[r][q4 * 8];
        }
#pragma unroll
        for (int sm = 0; sm < 2; sm++)
#pragma unroll
            for (int sn = 0; sn < 4; sn++) {
                f32x4 a = acc[sm][sn];
                a = MFMA16(ah[sm], bh8[sn], a);
                a = MFMA16(ah[sm], bl8[sn], a);
                a = MFMA16(al[sm], bh8[sn], a);
                acc[sm][sn] = a;
            }
        __syncthreads();
    }

    // ---- epilogue: bias + bf16 store into q / (k + kT) ----
#pragma unroll
    for (int sm = 0; sm < 2; sm++) {
#pragma unroll
        for (int sn = 0; sn < 4; sn++) {
            int coln = ntile * 128 + wn * 64 + sn * 16 + l15;        // 0..2047
            float bias = (ntile < 8) ? bq[coln] : bk[coln - 1024];
#pragma unroll
            for (int reg = 0; reg < 4; reg++) {
                int m = m0 + wm * 32 + sm * 16 + q4 * 4 + reg;       // 0..8191
                int bb = m >> 10, ss = m & 1023;
                float val = acc[sm][sn][reg] + bias;
                unsigned short vb = f2b(val);
                if (ntile < 8) {
                    int hh = coln >> 6, d = coln & 63;
                    qbf[(((size_t)(bb * 16 + hh) * 1024) + ss) * 64 + d] = vb;
                } else {
                    int ck = coln - 1024;
                    int hh = ck >> 6, d = ck & 63;
                    kbf[(((size_t)(bb * 16 + hh) * 1024) + ss) * 64 + d] = vb;
                    kTbf[(((size_t)(bb * 16 + hh) * 64) + d) * 1024 + ss] = vb;
                }
            }
        }
    }
}

// ---------------- fused attention -------------------------------------------------
// grid: 8192 blocks = (bh 0..127) * 64 l-tiles of 16 query rows; 512 threads (8 waves).
// Wave w owns r-stripe [w*128,(w+1)*128): 8 subtiles of 16x16 scores kept in VGPRs.
// rel terms: per subtile, Gq = Qtile @ Tband^T, Gk = Ktile @ Tband^T (band = 32 rows),
// routed through per-wave LDS scratch, diagonal-gathered (conflict-free strides 33/35).
__global__ __launch_bounds__(512)
void attn(const unsigned short* __restrict__ qbf, const unsigned short* __restrict__ kbf,
          const unsigned short* __restrict__ kTbf, const unsigned short* __restrict__ Tbf,
          float* __restrict__ out)
{
    __shared__ float smem[8704];          // G scratch -> probs (bf16) -> ctx partials
    __shared__ float red[2][8][16];
    __shared__ float fin[2][16];

    const int t = threadIdx.x;
    const int lane = t & 63, w = t >> 6;
    const int q4 = lane >> 4, l15 = lane & 15;
    const int bh = blockIdx.x >> 6, lt = blockIdx.x & 63;
    const int la = lt * 16;

    const unsigned short* qb = qbf + (size_t)bh * (1024 * 64);
    const unsigned short* kb = kbf + (size_t)bh * (1024 * 64);
    const unsigned short* kT = kTbf + (size_t)bh * (64 * 1024);

    const s16x8 qf0 = *(const s16x8*)(qb + (la + l15) * 64 + q4 * 8);
    const s16x8 qf1 = *(const s16x8*)(qb + (la + l15) * 64 + 32 + q4 * 8);

    float* Gq = smem + w * 1088;          // 16 rows, stride 33
    float* Gk = smem + w * 1088 + 528;    // 16 rows, stride 35

    f32x4 sacc[8];
#pragma unroll
    for (int s8 = 0; s8 < 8; s8++) {
        const int ra = w * 128 + s8 * 16;
        const s16x8 kf0 = *(const s16x8*)(kb + (ra + l15) * 64 + q4 * 8);
        const s16x8 kf1 = *(const s16x8*)(kb + (ra + l15) * 64 + 32 + q4 * 8);
        f32x4 a = (f32x4){0.f, 0.f, 0.f, 0.f};
        a = MFMA16(qf0, kf0, a);
        a = MFMA16(qf1, kf1, a);

        const int jb = la - ra + 1008;    // band base: j = (l-r)+1023 - 15, in [0,2016]
        const unsigned short* Tp = Tbf + (size_t)jb * 64;
        const s16x8 t00 = *(const s16x8*)(Tp + l15 * 64 + q4 * 8);
        const s16x8 t01 = *(const s16x8*)(Tp + l15 * 64 + 32 + q4 * 8);
        const s16x8 t10 = *(const s16x8*)(Tp + (16 + l15) * 64 + q4 * 8);
        const s16x8 t11 = *(const s16x8*)(Tp + (16 + l15) * 64 + 32 + q4 * 8);

        f32x4 g0 = (f32x4){0.f,0.f,0.f,0.f}, g1 = (f32x4){0.f,0.f,0.f,0.f};
        f32x4 h0 = (f32x4){0.f,0.f,0.f,0.f}, h1 = (f32x4){0.f,0.f,0.f,0.f};
        g0 = MFMA16(qf0, t00, g0); g0 = MFMA16(qf1, t01, g0);
        g1 = MFMA16(qf0, t10, g1); g1 = MFMA16(qf1, t11, g1);
        h0 = MFMA16(kf0, t00, h0); h0 = MFMA16(kf1, t01, h0);
        h1 = MFMA16(kf0, t10, h1); h1 = MFMA16(kf1, t11, h1);

#pragma unroll
        for (int reg = 0; reg < 4; reg++) {
            int li = q4 * 4 + reg;
            Gq[li * 33 + l15]      = g0[reg];
            Gq[li * 33 + 16 + l15] = g1[reg];
            Gk[li * 35 + l15]      = h0[reg];
            Gk[li * 35 + 16 + l15] = h1[reg];
        }
#pragma unroll
        for (int reg = 0; reg < 4; reg++) {
            int li = q4 * 4 + reg;
            int n  = li - l15 + 15;       // 0..30
            a[reg] += Gq[li * 33 + n] + Gk[l15 * 35 + n];
        }
        sacc[s8] = a;
    }

    // ---- softmax: row max ----
    float rmax[4];
#pragma unroll
    for (int reg = 0; reg < 4; reg++) {
        float m = sacc[0][reg];
#pragma unroll
        for (int s8 = 1; s8 < 8; s8++) m = fmaxf(m, sacc[s8][reg]);
        m *= 0.125f;
        m = fmaxf(m, __shfl_xor(m, 1));
        m = fmaxf(m, __shfl_xor(m, 2));
        m = fmaxf(m, __shfl_xor(m, 4));
        m = fmaxf(m, __shfl_xor(m, 8));
        rmax[reg] = m;
    }
    if (l15 == 0) {
#pragma unroll
        for (int reg = 0; reg < 4; reg++) red[0][w][q4 * 4 + reg] = rmax[reg];
    }
    __syncthreads();                                   // A (also: all score loops done)
    if (t < 16) {
        float m = red[0][0][t];
#pragma unroll
        for (int ww = 1; ww < 8; ww++) m = fmaxf(m, red[0][ww][t]);
        fin[0][t] = m;
    }
    __syncthreads();                                   // B

    // ---- exp, unnormalized probs -> LDS (bf16, row stride 1032), row sums ----
    unsigned short* probs = (unsigned short*)smem;
    float Mv[4], psum[4];
#pragma unroll
    for (int reg = 0; reg < 4; reg++) { Mv[reg] = fin[0][q4 * 4 + reg]; psum[reg] = 0.f; }
#pragma unroll
    for (int s8 = 0; s8 < 8; s8++) {
#pragma unroll
        for (int reg = 0; reg < 4; reg++) {
            float z = sacc[s8][reg] * 0.125f - Mv[reg];
            float p = __expf(z);
            psum[reg] += p;
            probs[(q4 * 4 + reg) * 1032 + w * 128 + s8 * 16 + l15] = f2b(p);
        }
    }
#pragma unroll
    for (int reg = 0; reg < 4; reg++) {
        float s = psum[reg];
        s += __shfl_xor(s, 1);
        s += __shfl_xor(s, 2);
        s += __shfl_xor(s, 4);
        s += __shfl_xor(s, 8);
        psum[reg] = s;
    }
    if (l15 == 0) {
#pragma unroll
        for (int reg = 0; reg < 4; reg++) red[1][w][q4 * 4 + reg] = psum[reg];
    }
    __syncthreads();                                   // C
    if (t < 16) {
        float s = 0.f;
#pragma unroll
        for (int ww = 0; ww < 8; ww++) s += red[1][ww][t];
        fin[1][t] = 1.0f / s;
    }
    __syncthreads();                                   // D

    // ---- PV: wave w handles K-chunk [w*128,(w+1)*128), all 64 d-cols ----
    f32x4 pacc[4];
#pragma unroll
    for (int n = 0; n < 4; n++) pacc[n] = (f32x4){0.f, 0.f, 0.f, 0.f};
#pragma unroll
    for (int kbk = 0; kbk < 4; kbk++) {
        const int ko = w * 128 + kbk * 32;
        const s16x8 pf = *(const s16x8*)(probs + l15 * 1032 + ko + q4 * 8);
#pragma unroll
        for (int n = 0; n < 4; n++) {
            const s16x8 vf = *(const s16x8*)(kT + (size_t)(n * 16 + l15) * 1024 + ko + q4 * 8);
            pacc[n] = MFMA16(pf, vf, pacc[n]);
        }
    }
    __syncthreads();                                   // E (all probs reads done)

    // ---- per-wave ctx partials to LDS (stride 65), tree-reduce, write out ----
#pragma unroll
    for (int n = 0; n < 4; n++)
#pragma unroll
        for (int reg = 0; reg < 4; reg++)
            smem[w * 1040 + (q4 * 4 + reg) * 65 + n * 16 + l15] = pacc[n][reg];
    __syncthreads();                                   // F

    const int b0 = bh >> 4, hh = bh & 15;
#pragma unroll
    for (int rep = 0; rep < 2; rep++) {
        int idx = t + rep * 512;
        int li = idx >> 6, dc = idx & 63;
        float sum = 0.f;
#pragma unroll
        for (int ww = 0; ww < 8; ww++) sum += smem[ww * 1040 + li * 65 + dc];
        sum *= fin[1][li];
        out[((size_t)(b0 * 1024 + la + li) * 1024) + hh * 64 + dc] = sum;
    }
}

// ---------------- launch ----------------------------------------------------------
extern "C" void kernel_launch(void* const* d_in, const int* in_sizes, int n_in,
                              void* d_out, int out_size, void* d_ws, size_t ws_size,
                              hipStream_t stream) {
    (void)in_sizes; (void)n_in; (void)out_size; (void)ws_size;
    const float* Hs = (const float*)d_in[0];
    const float* Wq = (const float*)d_in[1];
    const float* bq = (const float*)d_in[2];
    const float* Wk = (const float*)d_in[3];
    const float* bk = (const float*)d_in[4];
    // d_in[5], d_in[6] (Wv, bv) intentionally unused: reference's v uses the k projection.
    const float* Tt = (const float*)d_in[7];
    float* out = (float*)d_out;

    unsigned short* qbf  = (unsigned short*)d_ws;
    unsigned short* kbf  = qbf + (size_t)8 * 16 * 1024 * 64;   // 8388608 elems each
    unsigned short* kTbf = kbf + (size_t)8 * 16 * 1024 * 64;
    unsigned short* Tbf  = kTbf + (size_t)8 * 16 * 1024 * 64;  // 2048*64 elems

    hipLaunchKernelGGL(prep_table, dim3(512), dim3(256), 0, stream, Tt, Tbf);
    hipLaunchKernelGGL(proj_gemm, dim3(1024), dim3(512), 0, stream,
                       Hs, Wq, bq, Wk, bk, qbf, kbf, kTbf);
    hipLaunchKernelGGL(attn, dim3(8192), dim3(512), 0, stream,
                       qbf, kbf, kTbf, Tbf, out);
}